// Round 1
// baseline (1328.172 us; speedup 1.0000x reference)
//
#include <hip/hip_runtime.h>

#define HID 128
#define LN_EPS 1e-5f

// z := (1+eps) * h   (float4-vectorized, grid-stride)
__global__ __launch_bounds__(256) void k_init(const float* __restrict__ h,
                                              const float* __restrict__ eps,
                                              float* __restrict__ z, int n4) {
  const float c = 1.0f + eps[0];
  const int stride = gridDim.x * blockDim.x;
  for (int i = blockIdx.x * blockDim.x + threadIdx.x; i < n4; i += stride) {
    float4 v = reinterpret_cast<const float4*>(h)[i];
    v.x *= c; v.y *= c; v.z *= c; v.w *= c;
    reinterpret_cast<float4*>(z)[i] = v;
  }
}

// z[dst] += h[src] for each edge; 32 lanes per edge, float4 per lane.
__global__ __launch_bounds__(256) void k_scatter(const float* __restrict__ h,
                                                 const int* __restrict__ ei,
                                                 float* z, int nE) {
  const int gid = blockIdx.x * 256 + threadIdx.x;
  const int e = gid >> 5;
  if (e >= nE) return;
  const int lane = gid & 31;
  const int s = ei[e];        // edge_index[0] = src
  const int d = ei[nE + e];   // edge_index[1] = dst
  const float4 v = *reinterpret_cast<const float4*>(h + (size_t)s * HID + lane * 4);
  float* zp = z + (size_t)d * HID + lane * 4;
  atomicAdd(zp + 0, v.x);
  atomicAdd(zp + 1, v.y);
  atomicAdd(zp + 2, v.z);
  atomicAdd(zp + 3, v.w);
}

// out[i][j] = act( sum_k zin[i][k] * W[j][k] + bias[j] ) with
// MODE 0: ReLU;  MODE 1: +h residual, LayerNorm(gamma,beta), ReLU.
// 16 rows per block, 256 threads: thread = (row = t>>4, 8 cols = (t&15)*8).
// W^T staged in LDS in two k-halves (pad 132 kills bank conflicts).
// Safe in-place (out may alias zin): rows staged to LDS before any global write.
template <int MODE>
__global__ __launch_bounds__(256) void k_gemm(const float* zin,
                                              const float* __restrict__ W,
                                              const float* __restrict__ bias,
                                              const float* __restrict__ h,
                                              const float* __restrict__ gamma,
                                              const float* __restrict__ beta,
                                              float* out) {
  __shared__ float zs[16][132];
  __shared__ float wt[64][132];
  const int t = threadIdx.x;
  const int row0 = blockIdx.x * 16;

  // stage z tile: 16 rows x 128 = 512 float4, coalesced
  for (int i = t; i < 512; i += 256) {
    const int r = i >> 5;
    const int q = i & 31;
    float4 v = *reinterpret_cast<const float4*>(zin + (size_t)(row0 + r) * HID + q * 4);
    *reinterpret_cast<float4*>(&zs[r][q * 4]) = v;
  }

  const int row = t >> 4;
  const int colg = (t & 15) * 8;
  float acc[8];
#pragma unroll
  for (int c = 0; c < 8; ++c) acc[c] = 0.f;

  for (int half = 0; half < 2; ++half) {
    if (half) __syncthreads();  // wt reuse hazard
    // stage wt[kk][j] = W[j][half*64+kk] : 8192 floats, coalesced reads
    for (int i = t; i < 2048; i += 256) {
      const int j = i >> 4;
      const int q = i & 15;
      float4 v = *reinterpret_cast<const float4*>(W + j * HID + half * 64 + q * 4);
      wt[q * 4 + 0][j] = v.x;
      wt[q * 4 + 1][j] = v.y;
      wt[q * 4 + 2][j] = v.z;
      wt[q * 4 + 3][j] = v.w;
    }
    __syncthreads();  // also covers zs on first iteration
#pragma unroll 8
    for (int kk = 0; kk < 64; ++kk) {
      const float zv = zs[row][half * 64 + kk];
      const float4 w0 = *reinterpret_cast<const float4*>(&wt[kk][colg]);
      const float4 w1 = *reinterpret_cast<const float4*>(&wt[kk][colg + 4]);
      acc[0] = fmaf(zv, w0.x, acc[0]);
      acc[1] = fmaf(zv, w0.y, acc[1]);
      acc[2] = fmaf(zv, w0.z, acc[2]);
      acc[3] = fmaf(zv, w0.w, acc[3]);
      acc[4] = fmaf(zv, w1.x, acc[4]);
      acc[5] = fmaf(zv, w1.y, acc[5]);
      acc[6] = fmaf(zv, w1.z, acc[6]);
      acc[7] = fmaf(zv, w1.w, acc[7]);
    }
  }

  const float4 b0 = *reinterpret_cast<const float4*>(bias + colg);
  const float4 b1 = *reinterpret_cast<const float4*>(bias + colg + 4);
  float v[8];
  v[0] = acc[0] + b0.x; v[1] = acc[1] + b0.y; v[2] = acc[2] + b0.z; v[3] = acc[3] + b0.w;
  v[4] = acc[4] + b1.x; v[5] = acc[5] + b1.y; v[6] = acc[6] + b1.z; v[7] = acc[7] + b1.w;

  float* orow = out + (size_t)(row0 + row) * HID + colg;

  if (MODE == 0) {
#pragma unroll
    for (int c = 0; c < 8; ++c) v[c] = fmaxf(v[c], 0.f);
    float4 o0 = {v[0], v[1], v[2], v[3]};
    float4 o1 = {v[4], v[5], v[6], v[7]};
    *reinterpret_cast<float4*>(orow) = o0;
    *reinterpret_cast<float4*>(orow + 4) = o1;
  } else {
    const float* hrow = h + (size_t)(row0 + row) * HID + colg;
    const float4 h0 = *reinterpret_cast<const float4*>(hrow);
    const float4 h1 = *reinterpret_cast<const float4*>(hrow + 4);
    v[0] += h0.x; v[1] += h0.y; v[2] += h0.z; v[3] += h0.w;
    v[4] += h1.x; v[5] += h1.y; v[6] += h1.z; v[7] += h1.w;

    float s = 0.f, ss = 0.f;
#pragma unroll
    for (int c = 0; c < 8; ++c) { s += v[c]; ss += v[c] * v[c]; }
    // row = 16 contiguous lanes (16-aligned): xor-reduce within the group
#pragma unroll
    for (int m = 1; m < 16; m <<= 1) {
      s += __shfl_xor(s, m, 64);
      ss += __shfl_xor(ss, m, 64);
    }
    const float mu = s * (1.f / 128.f);
    const float var = ss * (1.f / 128.f) - mu * mu;
    const float rstd = rsqrtf(var + LN_EPS);

    const float4 g0 = *reinterpret_cast<const float4*>(gamma + colg);
    const float4 g1 = *reinterpret_cast<const float4*>(gamma + colg + 4);
    const float4 be0 = *reinterpret_cast<const float4*>(beta + colg);
    const float4 be1 = *reinterpret_cast<const float4*>(beta + colg + 4);
    const float gg[8] = {g0.x, g0.y, g0.z, g0.w, g1.x, g1.y, g1.z, g1.w};
    const float bb[8] = {be0.x, be0.y, be0.z, be0.w, be1.x, be1.y, be1.z, be1.w};
#pragma unroll
    for (int c = 0; c < 8; ++c) {
      const float o = (v[c] - mu) * rstd * gg[c] + bb[c];
      v[c] = fmaxf(o, 0.f);
    }
    float4 o0 = {v[0], v[1], v[2], v[3]};
    float4 o1 = {v[4], v[5], v[6], v[7]};
    *reinterpret_cast<float4*>(orow) = o0;
    *reinterpret_cast<float4*>(orow + 4) = o1;
  }
}

extern "C" void kernel_launch(void* const* d_in, const int* in_sizes, int n_in,
                              void* d_out, int out_size, void* d_ws, size_t ws_size,
                              hipStream_t stream) {
  const float* h     = (const float*)d_in[0];
  const int*   ei    = (const int*)d_in[1];
  const float* W1    = (const float*)d_in[2];
  const float* b1    = (const float*)d_in[3];
  const float* W2    = (const float*)d_in[4];
  const float* b2    = (const float*)d_in[5];
  const float* eps   = (const float*)d_in[6];
  const float* gamma = (const float*)d_in[7];
  const float* beta  = (const float*)d_in[8];

  const int nNodes = in_sizes[0] / HID;     // 50000
  const int nE     = in_sizes[1] / 2;       // 640000
  const int n4     = in_sizes[0] / 4;

  float* z = (float*)d_out;  // use d_out as the z/agg buffer (all later steps are row-local in-place)

  k_init<<<2048, 256, 0, stream>>>(h, eps, z, n4);

  const int sblocks = (nE * 32 + 255) / 256;  // 80000
  k_scatter<<<sblocks, 256, 0, stream>>>(h, ei, z, nE);

  const int gblocks = nNodes / 16;  // 3125 (50000 divisible by 16)
  k_gemm<0><<<gblocks, 256, 0, stream>>>(z, W1, b1, nullptr, nullptr, nullptr, z);
  k_gemm<1><<<gblocks, 256, 0, stream>>>(z, W2, b2, h, gamma, beta, z);
}

// Round 2
// 459.513 us; speedup vs baseline: 2.8904x; 2.8904x over previous
//
#include <hip/hip_runtime.h>

#define HID 128
#define LN_EPS 1e-5f

// ---------------- CSR build (counting sort by dst) ----------------

// counts[dst]++ per edge
__global__ __launch_bounds__(256) void k_count(const int* __restrict__ ei,
                                               int* __restrict__ counts, int nE) {
  const int e = blockIdx.x * 256 + threadIdx.x;
  if (e >= nE) return;
  atomicAdd(&counts[ei[nE + e]], 1);
}

// single-block exclusive scan of counts -> offsets (n+1), also seeds cursors
__global__ __launch_bounds__(1024) void k_scan(const int* __restrict__ counts,
                                               int* __restrict__ offsets,
                                               int* __restrict__ cursors, int n) {
  __shared__ int part[1024];
  const int t = threadIdx.x;
  const int per = (n + 1023) / 1024;
  const int lo = min(t * per, n);
  const int hi = min(lo + per, n);
  int s = 0;
  for (int i = lo; i < hi; ++i) s += counts[i];
  int val = s;
  part[t] = val;
  __syncthreads();
  for (int off = 1; off < 1024; off <<= 1) {
    int other = (t >= off) ? part[t - off] : 0;
    __syncthreads();
    val += other;
    part[t] = val;
    __syncthreads();
  }
  int run = val - s;  // exclusive prefix of this chunk
  for (int i = lo; i < hi; ++i) {
    const int c = counts[i];
    offsets[i] = run;
    cursors[i] = run;
    run += c;
  }
  if (t == 1023) offsets[n] = run;
}

// esrc[cursor[dst]++] = src
__global__ __launch_bounds__(256) void k_bucket(const int* __restrict__ ei,
                                                int* __restrict__ cursors,
                                                int* __restrict__ esrc, int nE) {
  const int e = blockIdx.x * 256 + threadIdx.x;
  if (e >= nE) return;
  const int s = ei[e];
  const int d = ei[nE + e];
  const int pos = atomicAdd(&cursors[d], 1);
  esrc[pos] = s;
}

// ---------------- gather: z[n] = (1+eps)*h[n] + sum_{e in CSR[n]} h[esrc[e]] ----
// 32 lanes per node, float4 per lane, register accumulation, no atomics.
__global__ __launch_bounds__(256) void k_gather(const float* __restrict__ h,
                                                const int* __restrict__ offsets,
                                                const int* __restrict__ esrc,
                                                const float* __restrict__ eps,
                                                float* __restrict__ z, int nNodes) {
  const int gid = blockIdx.x * 256 + threadIdx.x;
  const int node = gid >> 5;
  if (node >= nNodes) return;
  const int lane = threadIdx.x & 31;
  const float c = 1.0f + eps[0];

  const float4 hv = *reinterpret_cast<const float4*>(h + (size_t)node * HID + lane * 4);
  float4 acc;
  acc.x = c * hv.x; acc.y = c * hv.y; acc.z = c * hv.z; acc.w = c * hv.w;

  const int beg = offsets[node];
  const int end = offsets[node + 1];
  int e = beg;
  for (; e + 1 < end; e += 2) {  // 2 independent row loads in flight
    const int s0 = esrc[e];
    const int s1 = esrc[e + 1];
    const float4 v0 = *reinterpret_cast<const float4*>(h + (size_t)s0 * HID + lane * 4);
    const float4 v1 = *reinterpret_cast<const float4*>(h + (size_t)s1 * HID + lane * 4);
    acc.x += v0.x + v1.x; acc.y += v0.y + v1.y;
    acc.z += v0.z + v1.z; acc.w += v0.w + v1.w;
  }
  if (e < end) {
    const int s0 = esrc[e];
    const float4 v0 = *reinterpret_cast<const float4*>(h + (size_t)s0 * HID + lane * 4);
    acc.x += v0.x; acc.y += v0.y; acc.z += v0.z; acc.w += v0.w;
  }
  *reinterpret_cast<float4*>(z + (size_t)node * HID + lane * 4) = acc;
}

// ---------------- fused GEMM + epilogue (unchanged from R1) ----------------
template <int MODE>
__global__ __launch_bounds__(256) void k_gemm(const float* zin,
                                              const float* __restrict__ W,
                                              const float* __restrict__ bias,
                                              const float* __restrict__ h,
                                              const float* __restrict__ gamma,
                                              const float* __restrict__ beta,
                                              float* out) {
  __shared__ float zs[16][132];
  __shared__ float wt[64][132];
  const int t = threadIdx.x;
  const int row0 = blockIdx.x * 16;

  for (int i = t; i < 512; i += 256) {
    const int r = i >> 5;
    const int q = i & 31;
    float4 v = *reinterpret_cast<const float4*>(zin + (size_t)(row0 + r) * HID + q * 4);
    *reinterpret_cast<float4*>(&zs[r][q * 4]) = v;
  }

  const int row = t >> 4;
  const int colg = (t & 15) * 8;
  float acc[8];
#pragma unroll
  for (int c = 0; c < 8; ++c) acc[c] = 0.f;

  for (int half = 0; half < 2; ++half) {
    if (half) __syncthreads();
    for (int i = t; i < 2048; i += 256) {
      const int j = i >> 4;
      const int q = i & 15;
      float4 v = *reinterpret_cast<const float4*>(W + j * HID + half * 64 + q * 4);
      wt[q * 4 + 0][j] = v.x;
      wt[q * 4 + 1][j] = v.y;
      wt[q * 4 + 2][j] = v.z;
      wt[q * 4 + 3][j] = v.w;
    }
    __syncthreads();
#pragma unroll 8
    for (int kk = 0; kk < 64; ++kk) {
      const float zv = zs[row][half * 64 + kk];
      const float4 w0 = *reinterpret_cast<const float4*>(&wt[kk][colg]);
      const float4 w1 = *reinterpret_cast<const float4*>(&wt[kk][colg + 4]);
      acc[0] = fmaf(zv, w0.x, acc[0]);
      acc[1] = fmaf(zv, w0.y, acc[1]);
      acc[2] = fmaf(zv, w0.z, acc[2]);
      acc[3] = fmaf(zv, w0.w, acc[3]);
      acc[4] = fmaf(zv, w1.x, acc[4]);
      acc[5] = fmaf(zv, w1.y, acc[5]);
      acc[6] = fmaf(zv, w1.z, acc[6]);
      acc[7] = fmaf(zv, w1.w, acc[7]);
    }
  }

  const float4 b0 = *reinterpret_cast<const float4*>(bias + colg);
  const float4 b1 = *reinterpret_cast<const float4*>(bias + colg + 4);
  float v[8];
  v[0] = acc[0] + b0.x; v[1] = acc[1] + b0.y; v[2] = acc[2] + b0.z; v[3] = acc[3] + b0.w;
  v[4] = acc[4] + b1.x; v[5] = acc[5] + b1.y; v[6] = acc[6] + b1.z; v[7] = acc[7] + b1.w;

  float* orow = out + (size_t)(row0 + row) * HID + colg;

  if (MODE == 0) {
#pragma unroll
    for (int c = 0; c < 8; ++c) v[c] = fmaxf(v[c], 0.f);
    float4 o0 = {v[0], v[1], v[2], v[3]};
    float4 o1 = {v[4], v[5], v[6], v[7]};
    *reinterpret_cast<float4*>(orow) = o0;
    *reinterpret_cast<float4*>(orow + 4) = o1;
  } else {
    const float* hrow = h + (size_t)(row0 + row) * HID + colg;
    const float4 h0 = *reinterpret_cast<const float4*>(hrow);
    const float4 h1 = *reinterpret_cast<const float4*>(hrow + 4);
    v[0] += h0.x; v[1] += h0.y; v[2] += h0.z; v[3] += h0.w;
    v[4] += h1.x; v[5] += h1.y; v[6] += h1.z; v[7] += h1.w;

    float s = 0.f, ss = 0.f;
#pragma unroll
    for (int c = 0; c < 8; ++c) { s += v[c]; ss += v[c] * v[c]; }
#pragma unroll
    for (int m = 1; m < 16; m <<= 1) {
      s += __shfl_xor(s, m, 64);
      ss += __shfl_xor(ss, m, 64);
    }
    const float mu = s * (1.f / 128.f);
    const float var = ss * (1.f / 128.f) - mu * mu;
    const float rstd = rsqrtf(var + LN_EPS);

    const float4 g0 = *reinterpret_cast<const float4*>(gamma + colg);
    const float4 g1 = *reinterpret_cast<const float4*>(gamma + colg + 4);
    const float4 be0 = *reinterpret_cast<const float4*>(beta + colg);
    const float4 be1 = *reinterpret_cast<const float4*>(beta + colg + 4);
    const float gg[8] = {g0.x, g0.y, g0.z, g0.w, g1.x, g1.y, g1.z, g1.w};
    const float bb[8] = {be0.x, be0.y, be0.z, be0.w, be1.x, be1.y, be1.z, be1.w};
#pragma unroll
    for (int c = 0; c < 8; ++c) {
      const float o = (v[c] - mu) * rstd * gg[c] + bb[c];
      v[c] = fmaxf(o, 0.f);
    }
    float4 o0 = {v[0], v[1], v[2], v[3]};
    float4 o1 = {v[4], v[5], v[6], v[7]};
    *reinterpret_cast<float4*>(orow) = o0;
    *reinterpret_cast<float4*>(orow + 4) = o1;
  }
}

extern "C" void kernel_launch(void* const* d_in, const int* in_sizes, int n_in,
                              void* d_out, int out_size, void* d_ws, size_t ws_size,
                              hipStream_t stream) {
  const float* h     = (const float*)d_in[0];
  const int*   ei    = (const int*)d_in[1];
  const float* W1    = (const float*)d_in[2];
  const float* b1    = (const float*)d_in[3];
  const float* W2    = (const float*)d_in[4];
  const float* b2    = (const float*)d_in[5];
  const float* eps   = (const float*)d_in[6];
  const float* gamma = (const float*)d_in[7];
  const float* beta  = (const float*)d_in[8];

  const int nNodes = in_sizes[0] / HID;  // 50000
  const int nE     = in_sizes[1] / 2;    // 640000

  // ws layout (ints): counts[n] | offsets[n+1] | cursors[n] | esrc[nE]  (~3.2 MB)
  int* counts  = (int*)d_ws;
  int* offsets = counts + nNodes;
  int* cursors = offsets + nNodes + 1;
  int* esrc    = cursors + nNodes;

  hipMemsetAsync(counts, 0, (size_t)nNodes * sizeof(int), stream);

  const int eblocks = (nE + 255) / 256;
  k_count<<<eblocks, 256, 0, stream>>>(ei, counts, nE);
  k_scan<<<1, 1024, 0, stream>>>(counts, offsets, cursors, nNodes);
  k_bucket<<<eblocks, 256, 0, stream>>>(ei, cursors, esrc, nE);

  float* z = (float*)d_out;  // d_out doubles as z buffer; later stages are row-local in-place
  const int gthreads = nNodes * 32;
  k_gather<<<(gthreads + 255) / 256, 256, 0, stream>>>(h, offsets, esrc, eps, z, nNodes);

  const int gblocks = nNodes / 16;
  k_gemm<0><<<gblocks, 256, 0, stream>>>(z, W1, b1, nullptr, nullptr, nullptr, z);
  k_gemm<1><<<gblocks, 256, 0, stream>>>(z, W2, b2, h, gamma, beta, z);
}

// Round 4
// 360.611 us; speedup vs baseline: 3.6831x; 1.2743x over previous
//
#include <hip/hip_runtime.h>

#define HID 128
#define LN_EPS 1e-5f

// ---------------- CSR build (counting sort by dst) ----------------

// counts[dst]++ per edge
__global__ __launch_bounds__(256) void k_count(const int* __restrict__ ei,
                                               int* __restrict__ counts, int nE) {
  const int e = blockIdx.x * 256 + threadIdx.x;
  if (e >= nE) return;
  atomicAdd(&counts[ei[nE + e]], 1);
}

// pass 1: per-block Hillis-Steele scan of 256 counts.
// offsets[i] = exclusive-within-block, bsum[b] = block total.
__global__ __launch_bounds__(256) void k_scan1(const int* __restrict__ counts,
                                               int* __restrict__ offsets,
                                               int* __restrict__ bsum, int n) {
  __shared__ int sm[256];
  const int t = threadIdx.x;
  const int i = blockIdx.x * 256 + t;
  const int v = (i < n) ? counts[i] : 0;
  int incl = v;
  sm[t] = incl;
  __syncthreads();
#pragma unroll
  for (int off = 1; off < 256; off <<= 1) {
    const int other = (t >= off) ? sm[t - off] : 0;
    __syncthreads();
    incl += other;
    sm[t] = incl;
    __syncthreads();
  }
  if (i < n) offsets[i] = incl - v;
  if (t == 255) bsum[blockIdx.x] = incl;
}

// pass 2: single block scans block totals -> ebase[b]; writes offsets[n]=total.
__global__ __launch_bounds__(256) void k_scan2(const int* __restrict__ bsum,
                                               int* __restrict__ ebase,
                                               int* __restrict__ offsets,
                                               int nb, int n) {
  __shared__ int sm[256];
  const int t = threadIdx.x;
  const int v = (t < nb) ? bsum[t] : 0;
  int incl = v;
  sm[t] = incl;
  __syncthreads();
#pragma unroll
  for (int off = 1; off < 256; off <<= 1) {
    const int other = (t >= off) ? sm[t - off] : 0;
    __syncthreads();
    incl += other;
    sm[t] = incl;
    __syncthreads();
  }
  if (t < nb) ebase[t] = incl - v;
  if (t == 255) offsets[n] = incl;  // zero-padded, so incl@255 == grand total
}

// pass 3: add block base; seed cursors.
__global__ __launch_bounds__(256) void k_scan3(int* __restrict__ offsets,
                                               int* __restrict__ cursors,
                                               const int* __restrict__ ebase, int n) {
  const int i = blockIdx.x * 256 + threadIdx.x;
  if (i >= n) return;
  const int o = offsets[i] + ebase[blockIdx.x];
  offsets[i] = o;
  cursors[i] = o;
}

// esrc[cursor[dst]++] = src
__global__ __launch_bounds__(256) void k_bucket(const int* __restrict__ ei,
                                                int* __restrict__ cursors,
                                                int* __restrict__ esrc, int nE) {
  const int e = blockIdx.x * 256 + threadIdx.x;
  if (e >= nE) return;
  const int s = ei[e];
  const int d = ei[nE + e];
  const int pos = atomicAdd(&cursors[d], 1);
  esrc[pos] = s;
}

// ---------------- gather: z[n] = (1+eps)*h[n] + sum_{e in CSR[n]} h[esrc[e]] ----
__global__ __launch_bounds__(256) void k_gather(const float* __restrict__ h,
                                                const int* __restrict__ offsets,
                                                const int* __restrict__ esrc,
                                                const float* __restrict__ eps,
                                                float* __restrict__ z, int nNodes) {
  const int gid = blockIdx.x * 256 + threadIdx.x;
  const int node = gid >> 5;
  if (node >= nNodes) return;
  const int lane = threadIdx.x & 31;
  const float c = 1.0f + eps[0];

  const float4 hv = *reinterpret_cast<const float4*>(h + (size_t)node * HID + lane * 4);
  float4 acc;
  acc.x = c * hv.x; acc.y = c * hv.y; acc.z = c * hv.z; acc.w = c * hv.w;

  const int beg = offsets[node];
  const int end = offsets[node + 1];
  int e = beg;
  for (; e + 1 < end; e += 2) {
    const int s0 = esrc[e];
    const int s1 = esrc[e + 1];
    const float4 v0 = *reinterpret_cast<const float4*>(h + (size_t)s0 * HID + lane * 4);
    const float4 v1 = *reinterpret_cast<const float4*>(h + (size_t)s1 * HID + lane * 4);
    acc.x += v0.x + v1.x; acc.y += v0.y + v1.y;
    acc.z += v0.z + v1.z; acc.w += v0.w + v1.w;
  }
  if (e < end) {
    const int s0 = esrc[e];
    const float4 v0 = *reinterpret_cast<const float4*>(h + (size_t)s0 * HID + lane * 4);
    acc.x += v0.x; acc.y += v0.y; acc.z += v0.z; acc.w += v0.w;
  }
  *reinterpret_cast<float4*>(z + (size_t)node * HID + lane * 4) = acc;
}

// ---------------- fused GEMM + epilogue (unchanged) ----------------
template <int MODE>
__global__ __launch_bounds__(256) void k_gemm(const float* zin,
                                              const float* __restrict__ W,
                                              const float* __restrict__ bias,
                                              const float* __restrict__ h,
                                              const float* __restrict__ gamma,
                                              const float* __restrict__ beta,
                                              float* out) {
  __shared__ float zs[16][132];
  __shared__ float wt[64][132];
  const int t = threadIdx.x;
  const int row0 = blockIdx.x * 16;

  for (int i = t; i < 512; i += 256) {
    const int r = i >> 5;
    const int q = i & 31;
    float4 v = *reinterpret_cast<const float4*>(zin + (size_t)(row0 + r) * HID + q * 4);
    *reinterpret_cast<float4*>(&zs[r][q * 4]) = v;
  }

  const int row = t >> 4;
  const int colg = (t & 15) * 8;
  float acc[8];
#pragma unroll
  for (int c = 0; c < 8; ++c) acc[c] = 0.f;

  for (int half = 0; half < 2; ++half) {
    if (half) __syncthreads();
    for (int i = t; i < 2048; i += 256) {
      const int j = i >> 4;
      const int q = i & 15;
      float4 v = *reinterpret_cast<const float4*>(W + j * HID + half * 64 + q * 4);
      wt[q * 4 + 0][j] = v.x;
      wt[q * 4 + 1][j] = v.y;
      wt[q * 4 + 2][j] = v.z;
      wt[q * 4 + 3][j] = v.w;
    }
    __syncthreads();
#pragma unroll 8
    for (int kk = 0; kk < 64; ++kk) {
      const float zv = zs[row][half * 64 + kk];
      const float4 w0 = *reinterpret_cast<const float4*>(&wt[kk][colg]);
      const float4 w1 = *reinterpret_cast<const float4*>(&wt[kk][colg + 4]);
      acc[0] = fmaf(zv, w0.x, acc[0]);
      acc[1] = fmaf(zv, w0.y, acc[1]);
      acc[2] = fmaf(zv, w0.z, acc[2]);
      acc[3] = fmaf(zv, w0.w, acc[3]);
      acc[4] = fmaf(zv, w1.x, acc[4]);
      acc[5] = fmaf(zv, w1.y, acc[5]);
      acc[6] = fmaf(zv, w1.z, acc[6]);
      acc[7] = fmaf(zv, w1.w, acc[7]);
    }
  }

  const float4 b0 = *reinterpret_cast<const float4*>(bias + colg);
  const float4 b1 = *reinterpret_cast<const float4*>(bias + colg + 4);
  float v[8];
  v[0] = acc[0] + b0.x; v[1] = acc[1] + b0.y; v[2] = acc[2] + b0.z; v[3] = acc[3] + b0.w;
  v[4] = acc[4] + b1.x; v[5] = acc[5] + b1.y; v[6] = acc[6] + b1.z; v[7] = acc[7] + b1.w;

  float* orow = out + (size_t)(row0 + row) * HID + colg;

  if (MODE == 0) {
#pragma unroll
    for (int c = 0; c < 8; ++c) v[c] = fmaxf(v[c], 0.f);
    float4 o0 = {v[0], v[1], v[2], v[3]};
    float4 o1 = {v[4], v[5], v[6], v[7]};
    *reinterpret_cast<float4*>(orow) = o0;
    *reinterpret_cast<float4*>(orow + 4) = o1;
  } else {
    const float* hrow = h + (size_t)(row0 + row) * HID + colg;
    const float4 h0 = *reinterpret_cast<const float4*>(hrow);
    const float4 h1 = *reinterpret_cast<const float4*>(hrow + 4);
    v[0] += h0.x; v[1] += h0.y; v[2] += h0.z; v[3] += h0.w;
    v[4] += h1.x; v[5] += h1.y; v[6] += h1.z; v[7] += h1.w;

    float s = 0.f, ss = 0.f;
#pragma unroll
    for (int c = 0; c < 8; ++c) { s += v[c]; ss += v[c] * v[c]; }
#pragma unroll
    for (int m = 1; m < 16; m <<= 1) {
      s += __shfl_xor(s, m, 64);
      ss += __shfl_xor(ss, m, 64);
    }
    const float mu = s * (1.f / 128.f);
    const float var = ss * (1.f / 128.f) - mu * mu;
    const float rstd = rsqrtf(var + LN_EPS);

    const float4 g0 = *reinterpret_cast<const float4*>(gamma + colg);
    const float4 g1 = *reinterpret_cast<const float4*>(gamma + colg + 4);
    const float4 be0 = *reinterpret_cast<const float4*>(beta + colg);
    const float4 be1 = *reinterpret_cast<const float4*>(beta + colg + 4);
    const float gg[8] = {g0.x, g0.y, g0.z, g0.w, g1.x, g1.y, g1.z, g1.w};
    const float bb[8] = {be0.x, be0.y, be0.z, be0.w, be1.x, be1.y, be1.z, be1.w};
#pragma unroll
    for (int c = 0; c < 8; ++c) {
      const float o = (v[c] - mu) * rstd * gg[c] + bb[c];
      v[c] = fmaxf(o, 0.f);
    }
    float4 o0 = {v[0], v[1], v[2], v[3]};
    float4 o1 = {v[4], v[5], v[6], v[7]};
    *reinterpret_cast<float4*>(orow) = o0;
    *reinterpret_cast<float4*>(orow + 4) = o1;
  }
}

extern "C" void kernel_launch(void* const* d_in, const int* in_sizes, int n_in,
                              void* d_out, int out_size, void* d_ws, size_t ws_size,
                              hipStream_t stream) {
  const float* h     = (const float*)d_in[0];
  const int*   ei    = (const int*)d_in[1];
  const float* W1    = (const float*)d_in[2];
  const float* b1    = (const float*)d_in[3];
  const float* W2    = (const float*)d_in[4];
  const float* b2    = (const float*)d_in[5];
  const float* eps   = (const float*)d_in[6];
  const float* gamma = (const float*)d_in[7];
  const float* beta  = (const float*)d_in[8];

  const int nNodes = in_sizes[0] / HID;  // 50000
  const int nE     = in_sizes[1] / 2;    // 640000
  const int nb     = (nNodes + 255) / 256;  // 196 scan blocks

  // ws layout (ints): counts[n] | offsets[n+1] | cursors[n] | esrc[nE] | bsum[nb] | ebase[nb]
  int* counts  = (int*)d_ws;
  int* offsets = counts + nNodes;
  int* cursors = offsets + nNodes + 1;
  int* esrc    = cursors + nNodes;
  int* bsum    = esrc + nE;
  int* ebase   = bsum + nb;

  hipMemsetAsync(counts, 0, (size_t)nNodes * sizeof(int), stream);

  const int eblocks = (nE + 255) / 256;
  k_count<<<eblocks, 256, 0, stream>>>(ei, counts, nE);
  k_scan1<<<nb, 256, 0, stream>>>(counts, offsets, bsum, nNodes);
  k_scan2<<<1, 256, 0, stream>>>(bsum, ebase, offsets, nb, nNodes);
  k_scan3<<<nb, 256, 0, stream>>>(offsets, cursors, ebase, nNodes);
  k_bucket<<<eblocks, 256, 0, stream>>>(ei, cursors, esrc, nE);

  float* z = (float*)d_out;  // d_out doubles as z buffer; later stages row-local in-place
  const int gthreads = nNodes * 32;
  k_gather<<<(gthreads + 255) / 256, 256, 0, stream>>>(h, offsets, esrc, eps, z, nNodes);

  const int gblocks = nNodes / 16;
  k_gemm<0><<<gblocks, 256, 0, stream>>>(z, W1, b1, nullptr, nullptr, nullptr, z);
  k_gemm<1><<<gblocks, 256, 0, stream>>>(z, W2, b2, h, gamma, beta, z);
}

// Round 5
// 244.187 us; speedup vs baseline: 5.4392x; 1.4768x over previous
//
#include <hip/hip_runtime.h>

#define HID 128
#define LN_EPS 1e-5f

typedef __attribute__((ext_vector_type(8))) short bf16x8;
typedef __attribute__((ext_vector_type(4))) float f32x4;

static __device__ __forceinline__ unsigned short f2bf(float f) {
  unsigned int x = __float_as_uint(f);
  x += 0x7fffu + ((x >> 16) & 1u);  // RNE
  return (unsigned short)(x >> 16);
}
static __device__ __forceinline__ float bflo(unsigned int u) { return __uint_as_float(u << 16); }
static __device__ __forceinline__ float bfhi(unsigned int u) { return __uint_as_float(u & 0xffff0000u); }

// ---------------- CSR build (counting sort by dst) ----------------
__global__ __launch_bounds__(256) void k_count(const int* __restrict__ ei,
                                               int* __restrict__ counts, int nE) {
  const int e = blockIdx.x * 256 + threadIdx.x;
  if (e >= nE) return;
  atomicAdd(&counts[ei[nE + e]], 1);
}

__global__ __launch_bounds__(256) void k_scan1(const int* __restrict__ counts,
                                               int* __restrict__ offsets,
                                               int* __restrict__ bsum, int n) {
  __shared__ int sm[256];
  const int t = threadIdx.x;
  const int i = blockIdx.x * 256 + t;
  const int v = (i < n) ? counts[i] : 0;
  int incl = v;
  sm[t] = incl;
  __syncthreads();
#pragma unroll
  for (int off = 1; off < 256; off <<= 1) {
    const int other = (t >= off) ? sm[t - off] : 0;
    __syncthreads();
    incl += other;
    sm[t] = incl;
    __syncthreads();
  }
  if (i < n) offsets[i] = incl - v;
  if (t == 255) bsum[blockIdx.x] = incl;
}

__global__ __launch_bounds__(256) void k_scan2(const int* __restrict__ bsum,
                                               int* __restrict__ ebase,
                                               int* __restrict__ offsets,
                                               int nb, int n) {
  __shared__ int sm[256];
  const int t = threadIdx.x;
  const int v = (t < nb) ? bsum[t] : 0;
  int incl = v;
  sm[t] = incl;
  __syncthreads();
#pragma unroll
  for (int off = 1; off < 256; off <<= 1) {
    const int other = (t >= off) ? sm[t - off] : 0;
    __syncthreads();
    incl += other;
    sm[t] = incl;
    __syncthreads();
  }
  if (t < nb) ebase[t] = incl - v;
  if (t == 255) offsets[n] = incl;
}

__global__ __launch_bounds__(256) void k_scan3(int* __restrict__ offsets,
                                               int* __restrict__ cursors,
                                               const int* __restrict__ ebase, int n) {
  const int i = blockIdx.x * 256 + threadIdx.x;
  if (i >= n) return;
  const int o = offsets[i] + ebase[blockIdx.x];
  offsets[i] = o;
  cursors[i] = o;
}

__global__ __launch_bounds__(256) void k_bucket(const int* __restrict__ ei,
                                                int* __restrict__ cursors,
                                                int* __restrict__ esrc, int nE) {
  const int e = blockIdx.x * 256 + threadIdx.x;
  if (e >= nE) return;
  const int s = ei[e];
  const int d = ei[nE + e];
  const int pos = atomicAdd(&cursors[d], 1);
  esrc[pos] = s;
}

// ---------------- f32 -> bf16 (packed pairs), grid-stride ----------------
__global__ __launch_bounds__(256) void k_tobf(const float* __restrict__ in,
                                              unsigned int* __restrict__ out, int n4) {
  const int stride = gridDim.x * 256;
  for (int i = blockIdx.x * 256 + threadIdx.x; i < n4; i += stride) {
    const float4 v = reinterpret_cast<const float4*>(in)[i];
    uint2 p;
    p.x = (unsigned)f2bf(v.x) | ((unsigned)f2bf(v.y) << 16);
    p.y = (unsigned)f2bf(v.z) | ((unsigned)f2bf(v.w) << 16);
    reinterpret_cast<uint2*>(out)[i] = p;
  }
}

// ---------------- gather (bf16): z[n] = (1+eps)*h[n] + sum h[esrc[e]] ----------------
// 32 lanes/node, 4 cols/lane (uint2 = 4 bf16), f32 accumulation.
__global__ __launch_bounds__(256) void k_gather(const unsigned short* __restrict__ hbf,
                                                const int* __restrict__ offsets,
                                                const int* __restrict__ esrc,
                                                const float* __restrict__ eps,
                                                unsigned short* __restrict__ zbf, int nNodes) {
  const int gid = blockIdx.x * 256 + threadIdx.x;
  const int node = gid >> 5;
  if (node >= nNodes) return;
  const int col4 = (threadIdx.x & 31) * 4;
  const float c = 1.0f + eps[0];

  const uint2 hv = *reinterpret_cast<const uint2*>(hbf + (size_t)node * HID + col4);
  float a0 = c * bflo(hv.x), a1 = c * bfhi(hv.x);
  float a2 = c * bflo(hv.y), a3 = c * bfhi(hv.y);

  const int beg = offsets[node], end = offsets[node + 1];
  int e = beg;
  for (; e + 1 < end; e += 2) {
    const int s0 = esrc[e], s1 = esrc[e + 1];
    const uint2 v0 = *reinterpret_cast<const uint2*>(hbf + (size_t)s0 * HID + col4);
    const uint2 v1 = *reinterpret_cast<const uint2*>(hbf + (size_t)s1 * HID + col4);
    a0 += bflo(v0.x) + bflo(v1.x);
    a1 += bfhi(v0.x) + bfhi(v1.x);
    a2 += bflo(v0.y) + bflo(v1.y);
    a3 += bfhi(v0.y) + bfhi(v1.y);
  }
  if (e < end) {
    const uint2 v0 = *reinterpret_cast<const uint2*>(hbf + (size_t)esrc[e] * HID + col4);
    a0 += bflo(v0.x); a1 += bfhi(v0.x); a2 += bflo(v0.y); a3 += bfhi(v0.y);
  }
  uint2 o;
  o.x = (unsigned)f2bf(a0) | ((unsigned)f2bf(a1) << 16);
  o.y = (unsigned)f2bf(a2) | ((unsigned)f2bf(a3) << 16);
  *reinterpret_cast<uint2*>(zbf + (size_t)node * HID + col4) = o;
}

// ---------------- MFMA GEMM 1: y1 = relu(z @ W1^T + b1), bf16 in/out, IN-PLACE ----------------
// mfma_f32_16x16x32_bf16. A: lane holds z[row0+(l&15)][(l>>4)*8 + j] (16B contiguous).
// B[k][col] = W[col][k]: lane holds W[nt*16+(l&15)][(l>>4)*8 + j] (16B contiguous, L1-hot).
// C/D: col = l&15, row = (l>>4)*4 + reg  [m89-verified].
__global__ __launch_bounds__(256) void k_mm1(unsigned short* zy,  // z in, y1 out (row-local)
                                             const unsigned short* __restrict__ wbf,
                                             const float* __restrict__ bias, int nTiles) {
  const int wave = threadIdx.x >> 6;
  const int l = threadIdx.x & 63;
  const int mtile = blockIdx.x * 4 + wave;
  if (mtile >= nTiles) return;
  const int row0 = mtile * 16;
  const int lr = l & 15;
  const int lq = l >> 4;

  bf16x8 a[4];
#pragma unroll
  for (int ks = 0; ks < 4; ++ks)
    a[ks] = *reinterpret_cast<const bf16x8*>(zy + (size_t)(row0 + lr) * HID + ks * 32 + lq * 8);

  f32x4 acc[8];
#pragma unroll
  for (int nt = 0; nt < 8; ++nt) acc[nt] = (f32x4){0.f, 0.f, 0.f, 0.f};

#pragma unroll
  for (int nt = 0; nt < 8; ++nt) {
    const unsigned short* wb = wbf + (size_t)(nt * 16 + lr) * HID + lq * 8;
#pragma unroll
    for (int ks = 0; ks < 4; ++ks) {
      const bf16x8 b = *reinterpret_cast<const bf16x8*>(wb + ks * 32);
      acc[nt] = __builtin_amdgcn_mfma_f32_16x16x32_bf16(a[ks], b, acc[nt], 0, 0, 0);
    }
  }

#pragma unroll
  for (int nt = 0; nt < 8; ++nt) {
    const int c = nt * 16 + lr;
    const float bs = bias[c];
#pragma unroll
    for (int r = 0; r < 4; ++r) {
      const int row = row0 + lq * 4 + r;
      zy[(size_t)row * HID + c] = f2bf(fmaxf(acc[nt][r] + bs, 0.f));
    }
  }
}

// ---------------- MFMA GEMM 2: out = relu(LN(y1 @ W2^T + b2 + h)) , f32 out ----------------
__global__ __launch_bounds__(256) void k_mm2(const unsigned short* __restrict__ y1,
                                             const unsigned short* __restrict__ wbf,
                                             const float* __restrict__ bias,
                                             const float* __restrict__ h,
                                             const float* __restrict__ gamma,
                                             const float* __restrict__ beta,
                                             float* __restrict__ out, int nTiles) {
  const int wave = threadIdx.x >> 6;
  const int l = threadIdx.x & 63;
  const int mtile = blockIdx.x * 4 + wave;
  if (mtile >= nTiles) return;
  const int row0 = mtile * 16;
  const int lr = l & 15;
  const int lq = l >> 4;

  bf16x8 a[4];
#pragma unroll
  for (int ks = 0; ks < 4; ++ks)
    a[ks] = *reinterpret_cast<const bf16x8*>(y1 + (size_t)(row0 + lr) * HID + ks * 32 + lq * 8);

  f32x4 acc[8];
#pragma unroll
  for (int nt = 0; nt < 8; ++nt) acc[nt] = (f32x4){0.f, 0.f, 0.f, 0.f};

#pragma unroll
  for (int nt = 0; nt < 8; ++nt) {
    const unsigned short* wb = wbf + (size_t)(nt * 16 + lr) * HID + lq * 8;
#pragma unroll
    for (int ks = 0; ks < 4; ++ks) {
      const bf16x8 b = *reinterpret_cast<const bf16x8*>(wb + ks * 32);
      acc[nt] = __builtin_amdgcn_mfma_f32_16x16x32_bf16(a[ks], b, acc[nt], 0, 0, 0);
    }
  }

  // residual + bias
#pragma unroll
  for (int nt = 0; nt < 8; ++nt) {
    const int c = nt * 16 + lr;
    const float bs = bias[c];
#pragma unroll
    for (int r = 0; r < 4; ++r) {
      const int row = row0 + lq * 4 + r;
      acc[nt][r] += bs + h[(size_t)row * HID + c];
    }
  }

  // LayerNorm per row: row (lq,r) spans the 16-lane group (lanes lq*16..lq*16+15) x 8 nt
  float mu_[4], rstd_[4];
#pragma unroll
  for (int r = 0; r < 4; ++r) {
    float s = 0.f, ss = 0.f;
#pragma unroll
    for (int nt = 0; nt < 8; ++nt) { const float v = acc[nt][r]; s += v; ss += v * v; }
#pragma unroll
    for (int m = 1; m < 16; m <<= 1) {
      s += __shfl_xor(s, m, 64);
      ss += __shfl_xor(ss, m, 64);
    }
    const float mu = s * (1.f / 128.f);
    const float var = ss * (1.f / 128.f) - mu * mu;
    mu_[r] = mu;
    rstd_[r] = rsqrtf(var + LN_EPS);
  }

#pragma unroll
  for (int nt = 0; nt < 8; ++nt) {
    const int c = nt * 16 + lr;
    const float g = gamma[c], be = beta[c];
#pragma unroll
    for (int r = 0; r < 4; ++r) {
      const int row = row0 + lq * 4 + r;
      const float o = (acc[nt][r] - mu_[r]) * rstd_[r] * g + be;
      out[(size_t)row * HID + c] = fmaxf(o, 0.f);
    }
  }
}

extern "C" void kernel_launch(void* const* d_in, const int* in_sizes, int n_in,
                              void* d_out, int out_size, void* d_ws, size_t ws_size,
                              hipStream_t stream) {
  const float* h     = (const float*)d_in[0];
  const int*   ei    = (const int*)d_in[1];
  const float* W1    = (const float*)d_in[2];
  const float* b1    = (const float*)d_in[3];
  const float* W2    = (const float*)d_in[4];
  const float* b2    = (const float*)d_in[5];
  const float* eps   = (const float*)d_in[6];
  const float* gamma = (const float*)d_in[7];
  const float* beta  = (const float*)d_in[8];

  const int nNodes = in_sizes[0] / HID;     // 50000
  const int nE     = in_sizes[1] / 2;       // 640000
  const int nb     = (nNodes + 255) / 256;  // 196

  // ws layout (ints, padded so bf16 sections are 16B-aligned):
  // counts[50000] | offsets[50001] | cursors[50000] | bsum[196] | ebase[196] | pad | esrc[640000]
  int* counts  = (int*)d_ws;
  int* offsets = counts + nNodes;                 // @ 50000
  int* cursors = offsets + nNodes + 1;            // @ 100001
  int* bsum    = cursors + nNodes;                // @ 150001
  int* ebase   = bsum + nb;                       // @ 150197
  int* esrc    = counts + 150400;                 // @ 150400 (byte 601600, 16B-aligned)
  unsigned short* hbf  = (unsigned short*)(esrc + nE);        // byte 3,161,600
  unsigned short* zbf  = hbf + (size_t)nNodes * HID;          // +12.8MB
  unsigned short* w1bf = zbf + (size_t)nNodes * HID;          // +12.8MB
  unsigned short* w2bf = w1bf + HID * HID;                    // +32KB  (total ~28.8MB)

  hipMemsetAsync(counts, 0, (size_t)nNodes * sizeof(int), stream);

  const int eblocks = (nE + 255) / 256;
  k_count<<<eblocks, 256, 0, stream>>>(ei, counts, nE);
  k_scan1<<<nb, 256, 0, stream>>>(counts, offsets, bsum, nNodes);
  k_scan2<<<1, 256, 0, stream>>>(bsum, ebase, offsets, nb, nNodes);
  k_scan3<<<nb, 256, 0, stream>>>(offsets, cursors, ebase, nNodes);
  k_bucket<<<eblocks, 256, 0, stream>>>(ei, cursors, esrc, nE);

  k_tobf<<<2048, 256, 0, stream>>>(h,  (unsigned int*)hbf,  nNodes * HID / 4);
  k_tobf<<<16,   256, 0, stream>>>(W1, (unsigned int*)w1bf, HID * HID / 4);
  k_tobf<<<16,   256, 0, stream>>>(W2, (unsigned int*)w2bf, HID * HID / 4);

  k_gather<<<(nNodes * 32 + 255) / 256, 256, 0, stream>>>(hbf, offsets, esrc, eps, zbf, nNodes);

  const int nTiles = nNodes / 16;                 // 3125
  const int mblocks = (nTiles + 3) / 4;           // 782
  k_mm1<<<mblocks, 256, 0, stream>>>(zbf, w1bf, b1, nTiles);
  k_mm2<<<mblocks, 256, 0, stream>>>(zbf, w2bf, b2, h, gamma, beta, (float*)d_out, nTiles);
}